// Round 1
// baseline (161.421 us; speedup 1.0000x reference)
//
#include <hip/hip_runtime.h>
#include <hip/hip_bf16.h>
#include <stdint.h>

#define HH 8
#define DD 128
#define MAXSEQ 2048
#define QBLK 256
#define KVB 64

typedef float f32x16 __attribute__((ext_vector_type(16)));
typedef short s16x8 __attribute__((ext_vector_type(8)));
typedef uint32_t u32x4v __attribute__((ext_vector_type(4)));

__device__ __forceinline__ unsigned short f2bf(float x) {
  union { float f; uint32_t u; } v; v.f = x;
  uint32_t u = v.u;
  return (unsigned short)((u + 0x7FFFu + ((u >> 16) & 1u)) >> 16);
}

// ---- prepass 1: K [T,H,D] f32 -> Kb [H,T,D] bf16 ----
__global__ void kconv(const float* __restrict__ k, unsigned short* __restrict__ kb, int T) {
  long i = (long)blockIdx.x * blockDim.x + threadIdx.x;
  long total = (long)T * HH * DD / 4;
  if (i >= total) return;
  long e = i * 4;
  int d = (int)(e % DD);
  int h = (int)((e / DD) % HH);
  long t = e / (DD * HH);
  float4 a = *(const float4*)(k + e);
  ushort4 o;
  o.x = f2bf(a.x); o.y = f2bf(a.y); o.z = f2bf(a.z); o.w = f2bf(a.w);
  *(ushort4*)(kb + ((size_t)h * T + (size_t)t) * DD + d) = o;
}

// ---- prepass 2: V [T,H,D] f32 -> Vt [H,D,T] bf16 (transpose) ----
__global__ void vtrans(const float* __restrict__ v, unsigned short* __restrict__ vt, int T) {
  __shared__ float tile[64][65];
  const int t0 = blockIdx.x * 64;
  const int d0 = blockIdx.y * 64;
  const int h = blockIdx.z;
  const int tid = threadIdx.x;
  const int row = tid >> 2;        // 0..63
  const int c0 = (tid & 3) * 16;   // 0,16,32,48
  const int tr = min(t0 + row, T - 1);
  const float* src = v + ((size_t)tr * HH + h) * DD + d0 + c0;
#pragma unroll
  for (int cc = 0; cc < 16; cc += 4) {
    float4 x = *(const float4*)(src + cc);
    tile[row][c0 + cc + 0] = x.x;
    tile[row][c0 + cc + 1] = x.y;
    tile[row][c0 + cc + 2] = x.z;
    tile[row][c0 + cc + 3] = x.w;
  }
  __syncthreads();
  unsigned short* dst = vt + ((size_t)h * DD + d0 + row) * (size_t)T + t0 + c0;
#pragma unroll
  for (int cc = 0; cc < 16; cc += 4) {
    if (t0 + c0 + cc + 3 < T) {
      ushort4 o;
      o.x = f2bf(tile[c0 + cc + 0][row]);
      o.y = f2bf(tile[c0 + cc + 1][row]);
      o.z = f2bf(tile[c0 + cc + 2][row]);
      o.w = f2bf(tile[c0 + cc + 3][row]);
      *(ushort4*)(dst + cc) = o;
    }
  }
}

// ---- main: 8-wave swapped-QK^T flash attention, 32x32x16 bf16 MFMA ----
__global__ __launch_bounds__(512, 2)
void attn_main(const float* __restrict__ q,
               const unsigned short* __restrict__ kb,
               const unsigned short* __restrict__ vt,
               const int* __restrict__ cuq,
               const int* __restrict__ cuk,
               float* __restrict__ out,
               int T, int BH) {
  const int bid = blockIdx.x;
  const int bh = bid % BH;
  const int qt = bid / BH;
  const int b = bh / HH, h = bh % HH;
  const int qs = cuq[b], qe = cuq[b + 1];
  const int ks = cuk[b], ke = cuk[b + 1];
  const int nq = min(qe - qs, MAXSEQ);
  const int nk = min(ke - ks, MAXSEQ);
  if (qt * QBLK >= nq || nk <= 0) return;

  const int tid = threadIdx.x;
  const int wave = tid >> 6;
  const int lane = tid & 63;
  const int lo = lane & 31;
  const int hi = lane >> 5;

  __shared__ __align__(16) unsigned short Kl[KVB * DD];  // [key][d], xor-swizzled
  __shared__ __align__(16) unsigned short Vl[DD * KVB];  // [d][key], xor-swizzled

  // Q fragments (B-operand of S^T = K * Q^T); fold 1/sqrt(D)*log2(e)
  const float SC = (1.0f / 11.313708498984761f) * 1.4426950408889634f;
  const int qrow = qt * QBLK + wave * 32 + lo;
  const int qg = qs + min(qrow, nq - 1);
  const float* qp = q + ((size_t)qg * HH + h) * DD;
  s16x8 qf[8];
#pragma unroll
  for (int s = 0; s < 8; ++s) {
    const float* p0 = qp + s * 16 + hi * 8;
    float4 a = *(const float4*)(p0);
    float4 c = *(const float4*)(p0 + 4);
    union { unsigned short us[8]; s16x8 v; } u;
    u.us[0] = f2bf(a.x * SC); u.us[1] = f2bf(a.y * SC);
    u.us[2] = f2bf(a.z * SC); u.us[3] = f2bf(a.w * SC);
    u.us[4] = f2bf(c.x * SC); u.us[5] = f2bf(c.y * SC);
    u.us[6] = f2bf(c.z * SC); u.us[7] = f2bf(c.w * SC);
    qf[s] = u.v;
  }

  f32x16 Oa[4];
#pragma unroll
  for (int i = 0; i < 4; ++i)
#pragma unroll
    for (int r = 0; r < 16; ++r) Oa[i][r] = 0.0f;

  float m_run = -__builtin_inff();
  float l_run = 0.0f;
  const unsigned short* kbh = kb + (size_t)h * T * DD;
  const unsigned short* vth = vt + (size_t)h * DD * (size_t)T;

  const int nkt = (nk + KVB - 1) / KVB;
  for (int kt = 0; kt < nkt; ++kt) {
    const int k0 = ks + kt * KVB;

    // ---- stage K (64x128) and Vt (128x64) as bf16, xor-swizzled ----
    {
      const int seg = tid & 15;
#pragma unroll
      for (int p2 = 0; p2 < 2; ++p2) {
        const int key = p2 * 32 + (tid >> 4);
        const int gk = min(k0 + key, T - 1);
        u32x4v val = *(const u32x4v*)(kbh + (size_t)gk * DD + seg * 8);
        const int idx = (key * DD + seg * 8) ^ ((key & 7) << 3);
        *(u32x4v*)(&Kl[idx]) = val;
      }
      const int sg = tid & 7;
#pragma unroll
      for (int p2 = 0; p2 < 2; ++p2) {
        const int dr = p2 * 64 + (tid >> 3);
        const int tc = min(k0 + sg * 8, T - 8);
        u32x4v val = *(const u32x4v*)(vth + (size_t)dr * T + tc);
        const int idx = (dr * KVB + sg * 8) ^ ((dr & 7) << 3);
        *(u32x4v*)(&Vl[idx]) = val;
      }
    }
    __syncthreads();

    // ---- S^T = K * Q^T  (two 32x32 tiles over 64 keys) ----
    f32x16 st0, st1;
#pragma unroll
    for (int r = 0; r < 16; ++r) { st0[r] = 0.0f; st1[r] = 0.0f; }
#pragma unroll
    for (int s = 0; s < 8; ++s) {
      {
        const int key = lo;
        const int idx = (key * DD + s * 16 + hi * 8) ^ ((key & 7) << 3);
        s16x8 kf = *(const s16x8*)(&Kl[idx]);
        st0 = __builtin_amdgcn_mfma_f32_32x32x16_bf16(kf, qf[s], st0, 0, 0, 0);
      }
      {
        const int key = 32 + lo;
        const int idx = (key * DD + s * 16 + hi * 8) ^ ((key & 7) << 3);
        s16x8 kf = *(const s16x8*)(&Kl[idx]);
        st1 = __builtin_amdgcn_mfma_f32_32x32x16_bf16(kf, qf[s], st1, 0, 0, 0);
      }
    }

    // mask keys beyond k_len (only in the last, partial tile)
    if (kt * KVB + KVB > nk) {
#pragma unroll
      for (int r = 0; r < 16; ++r) {
        const int base = (r & 3) + 8 * (r >> 2) + 4 * hi;
        if (kt * KVB + base >= nk) st0[r] = -__builtin_inff();
        if (kt * KVB + 32 + base >= nk) st1[r] = -__builtin_inff();
      }
    }

    // ---- online softmax (per q = lo; halves synced via shfl_xor 32) ----
    float tmax = -__builtin_inff();
#pragma unroll
    for (int r = 0; r < 16; ++r) tmax = fmaxf(tmax, fmaxf(st0[r], st1[r]));
    tmax = fmaxf(tmax, __shfl_xor(tmax, 32));
    const float m_new = fmaxf(m_run, tmax);
    const float alpha = __builtin_amdgcn_exp2f(m_run - m_new);

    float p[32];
    float psum = 0.0f;
#pragma unroll
    for (int r = 0; r < 16; ++r) {
      p[r] = __builtin_amdgcn_exp2f(st0[r] - m_new);
      p[16 + r] = __builtin_amdgcn_exp2f(st1[r] - m_new);
      psum += p[r] + p[16 + r];
    }
    psum += __shfl_xor(psum, 32);
    l_run = l_run * alpha + psum;
    m_run = m_new;

    // ---- pack P to bf16 chunks; exchange across halves ----
    // chunk c (c=0..7): keys 8c+4hi+e, e=0..3  ->  p[(c>>2)*16 + 4*(c&3) + e]
    uint32_t ownu[16];
#pragma unroll
    for (int c = 0; c < 8; ++c) {
      const int t = c >> 2, rb = 4 * (c & 3);
      ownu[c * 2 + 0] = (uint32_t)f2bf(p[t * 16 + rb + 0]) | ((uint32_t)f2bf(p[t * 16 + rb + 1]) << 16);
      ownu[c * 2 + 1] = (uint32_t)f2bf(p[t * 16 + rb + 2]) | ((uint32_t)f2bf(p[t * 16 + rb + 3]) << 16);
    }
    uint32_t recv[8];
#pragma unroll
    for (int k2 = 0; k2 < 4; ++k2) {
      const int cs = 2 * k2 + (hi ? 0 : 1);  // send what the partner needs
      recv[k2 * 2 + 0] = (uint32_t)__shfl_xor((int)ownu[cs * 2 + 0], 32);
      recv[k2 * 2 + 1] = (uint32_t)__shfl_xor((int)ownu[cs * 2 + 1], 32);
    }

    // ---- rescale O rows by alpha(q'), q' = crow(r,hi) ----
#pragma unroll
    for (int r = 0; r < 16; ++r) {
      const int src = (r & 3) + 8 * (r >> 2) + 4 * hi;
      const float af = __shfl(alpha, src);
      Oa[0][r] *= af; Oa[1][r] *= af; Oa[2][r] *= af; Oa[3][r] *= af;
    }

    // ---- O += P * V  (4 key-slots x 4 d-tiles) ----
#pragma unroll
    for (int ks2 = 0; ks2 < 4; ++ks2) {
      const int co = 2 * ks2 + hi;
      union { uint32_t u[4]; s16x8 v; } pu;
      pu.u[0] = hi ? recv[ks2 * 2 + 0] : ownu[co * 2 + 0];
      pu.u[1] = hi ? recv[ks2 * 2 + 1] : ownu[co * 2 + 1];
      pu.u[2] = hi ? ownu[co * 2 + 0] : recv[ks2 * 2 + 0];
      pu.u[3] = hi ? ownu[co * 2 + 1] : recv[ks2 * 2 + 1];
#pragma unroll
      for (int dt = 0; dt < 4; ++dt) {
        const int d = dt * 32 + lo;
        const int idx = (d * KVB + ks2 * 16 + hi * 8) ^ ((d & 7) << 3);
        s16x8 vf = *(const s16x8*)(&Vl[idx]);
        Oa[dt] = __builtin_amdgcn_mfma_f32_32x32x16_bf16(pu.v, vf, Oa[dt], 0, 0, 0);
      }
    }
    __syncthreads();
  }

  // ---- epilogue: out[q] = O[q]/l ----
  const float linv = 1.0f / l_run;
#pragma unroll
  for (int r = 0; r < 16; ++r) {
    const int src = (r & 3) + 8 * (r >> 2) + 4 * hi;
    const float li = __shfl(linv, src);
    const int qirow = qt * QBLK + wave * 32 + src;
    if (qirow < nq) {
      float* op = out + ((size_t)(qs + qirow) * HH + h) * DD;
      op[0 * 32 + lo] = Oa[0][r] * li;
      op[1 * 32 + lo] = Oa[1][r] * li;
      op[2 * 32 + lo] = Oa[2][r] * li;
      op[3 * 32 + lo] = Oa[3][r] * li;
    }
  }
}

extern "C" void kernel_launch(void* const* d_in, const int* in_sizes, int n_in,
                              void* d_out, int out_size, void* d_ws, size_t ws_size,
                              hipStream_t stream) {
  const float* q = (const float*)d_in[0];
  const float* k = (const float*)d_in[1];
  const float* v = (const float*)d_in[2];
  const int* cuq = (const int*)d_in[3];
  const int* cuk = (const int*)d_in[4];
  float* out = (float*)d_out;
  const int T = in_sizes[0] / (HH * DD);
  const int B = in_sizes[3] - 1;

  // zero output (ref scatters into zeros; also covers any uncovered rows)
  hipMemsetAsync(d_out, 0, (size_t)out_size * sizeof(float), stream);

  unsigned short* kb = (unsigned short*)d_ws;
  unsigned short* vt = kb + (size_t)T * HH * DD;
  const size_t need = (size_t)T * HH * DD * 2 * 2;
  if (ws_size < need) return;  // would corrupt memory otherwise; output stays 0 -> visible failure

  {
    long total4 = (long)T * HH * DD / 4;
    int blocks = (int)((total4 + 255) / 256);
    kconv<<<blocks, 256, 0, stream>>>(k, kb, T);
  }
  {
    dim3 g((unsigned)((T + 63) / 64), DD / 64, HH);
    vtrans<<<g, 256, 0, stream>>>(v, vt, T);
  }
  {
    const int BH = B * HH;
    const int scap = MAXSEQ < T ? MAXSEQ : T;
    const int qtiles = (scap + QBLK - 1) / QBLK;
    attn_main<<<BH * qtiles, 512, 0, stream>>>(q, kb, vt, cuq, cuk, out, T, BH);
  }
}

// Round 2
// 115.545 us; speedup vs baseline: 1.3970x; 1.3970x over previous
//
#include <hip/hip_runtime.h>
#include <hip/hip_bf16.h>
#include <stdint.h>

#define HH 8
#define DD 128
#define MAXSEQ 2048
#define QBLK 128
#define KVB 64

typedef float f32x16 __attribute__((ext_vector_type(16)));
typedef short s16x8 __attribute__((ext_vector_type(8)));
typedef uint32_t u32x4v __attribute__((ext_vector_type(4)));

__device__ __forceinline__ unsigned short f2bf(float x) {
  union { float f; uint32_t u; } v; v.f = x;
  uint32_t u = v.u;
  return (unsigned short)((u + 0x7FFFu + ((u >> 16) & 1u)) >> 16);
}

__device__ __forceinline__ void gload_lds16(const unsigned short* g, unsigned short* l) {
  __builtin_amdgcn_global_load_lds((const __attribute__((address_space(1))) void*)g,
                                   (__attribute__((address_space(3))) void*)l, 16, 0, 0);
}

// ---- prepass 1: K [T,H,D] f32 -> Kb [H,T,D] bf16 ----
__global__ void kconv(const float* __restrict__ k, unsigned short* __restrict__ kb, int T) {
  long i = (long)blockIdx.x * blockDim.x + threadIdx.x;
  long total = (long)T * HH * DD / 4;
  if (i >= total) return;
  long e = i * 4;
  int d = (int)(e % DD);
  int h = (int)((e / DD) % HH);
  long t = e / (DD * HH);
  float4 a = *(const float4*)(k + e);
  ushort4 o;
  o.x = f2bf(a.x); o.y = f2bf(a.y); o.z = f2bf(a.z); o.w = f2bf(a.w);
  *(ushort4*)(kb + ((size_t)h * T + (size_t)t) * DD + d) = o;
}

// ---- prepass 2: V [T,H,D] f32 -> Vt [H,D,T] bf16 (transpose) ----
__global__ void vtrans(const float* __restrict__ v, unsigned short* __restrict__ vt, int T) {
  __shared__ float tile[64][65];
  const int t0 = blockIdx.x * 64;
  const int d0 = blockIdx.y * 64;
  const int h = blockIdx.z;
  const int tid = threadIdx.x;
  const int row = tid >> 2;
  const int c0 = (tid & 3) * 16;
  const int tr = min(t0 + row, T - 1);
  const float* src = v + ((size_t)tr * HH + h) * DD + d0 + c0;
#pragma unroll
  for (int cc = 0; cc < 16; cc += 4) {
    float4 x = *(const float4*)(src + cc);
    tile[row][c0 + cc + 0] = x.x;
    tile[row][c0 + cc + 1] = x.y;
    tile[row][c0 + cc + 2] = x.z;
    tile[row][c0 + cc + 3] = x.w;
  }
  __syncthreads();
  unsigned short* dst = vt + ((size_t)h * DD + d0 + row) * (size_t)T + t0 + c0;
#pragma unroll
  for (int cc = 0; cc < 16; cc += 4) {
    if (t0 + c0 + cc + 3 < T) {
      ushort4 o;
      o.x = f2bf(tile[c0 + cc + 0][row]);
      o.y = f2bf(tile[c0 + cc + 1][row]);
      o.z = f2bf(tile[c0 + cc + 2][row]);
      o.w = f2bf(tile[c0 + cc + 3][row]);
      *(ushort4*)(dst + cc) = o;
    }
  }
}

// ---- main: 4-wave swapped-QK^T flash attention, dbuf LDS + global_load_lds ----
__global__ __launch_bounds__(256, 2)
void attn_main(const float* __restrict__ q,
               const unsigned short* __restrict__ kb,
               const unsigned short* __restrict__ vt,
               const int* __restrict__ cuq,
               const int* __restrict__ cuk,
               float* __restrict__ out,
               int T, int BH) {
  extern __shared__ __align__(16) unsigned short smem[];
  // layout (ushort elems): K buf b at b*8192 (64x128); V buf b at 16384 + b*8192 (128x64)

  const int bid = blockIdx.x;
  const int bh = bid % BH;
  const int qt = bid / BH;
  const int b = bh / HH, h = bh % HH;
  const int qs = cuq[b], qe = cuq[b + 1];
  const int ks = cuk[b], ke = cuk[b + 1];
  const int nq = min(qe - qs, MAXSEQ);
  const int nk = min(ke - ks, MAXSEQ);
  if (qt * QBLK >= nq || nk <= 0) return;

  const int tid = threadIdx.x;
  const int wave = tid >> 6;
  const int lane = tid & 63;
  const int lo = lane & 31;
  const int hi = lane >> 5;
  const int wbase8 = (tid & ~63) * 8;  // wave-uniform LDS elem base for staging

  const unsigned short* kbh = kb + (size_t)h * T * DD;
  const unsigned short* vth = vt + (size_t)h * DD * (size_t)T;

  // ---- Q fragments (B-operand of S^T = K * Q^T); fold 1/sqrt(D)*log2(e) ----
  const float SC = (1.0f / 11.313708498984761f) * 1.4426950408889634f;
  const int qrow = qt * QBLK + wave * 32 + lo;
  const int qg = qs + min(qrow, nq - 1);
  const float* qp = q + ((size_t)qg * HH + h) * DD;
  s16x8 qf[8];
#pragma unroll
  for (int s = 0; s < 8; ++s) {
    const float* p0 = qp + s * 16 + hi * 8;
    float4 a = *(const float4*)(p0);
    float4 c = *(const float4*)(p0 + 4);
    union { unsigned short us[8]; s16x8 v; } u;
    u.us[0] = f2bf(a.x * SC); u.us[1] = f2bf(a.y * SC);
    u.us[2] = f2bf(a.z * SC); u.us[3] = f2bf(a.w * SC);
    u.us[4] = f2bf(c.x * SC); u.us[5] = f2bf(c.y * SC);
    u.us[6] = f2bf(c.z * SC); u.us[7] = f2bf(c.w * SC);
    qf[s] = u.v;
  }

  f32x16 Oa[4];
#pragma unroll
  for (int i = 0; i < 4; ++i)
#pragma unroll
    for (int r = 0; r < 16; ++r) Oa[i][r] = 0.0f;

  float m_run = -__builtin_inff();
  float l_run = 0.0f;

  const int nkt = (nk + KVB - 1) / KVB;

  // ---- staging: pre-swizzled global source -> linear LDS (global_load_lds) ----
  auto stage = [&](int buf, int kt) {
    const int k0 = ks + kt * KVB;
    unsigned short* Kb = smem + buf * 8192;
    unsigned short* Vb = smem + 16384 + buf * 8192;
#pragma unroll
    for (int r = 0; r < 4; ++r) {
      const int g = r * 256 + tid;
      const int key = g >> 4, seg = g & 15;
      const int col = (seg * 8) ^ ((key & 7) << 3);
      const int gk = min(k0 + key, T - 1);
      gload_lds16(kbh + (size_t)gk * DD + col, Kb + (size_t)(r * 256) * 8 + wbase8);
    }
#pragma unroll
    for (int r = 0; r < 4; ++r) {
      const int g = r * 256 + tid;
      const int dr = g >> 3, sg = g & 7;
      const int colk = (sg * 8) ^ ((dr & 7) << 3);
      const int tc = min(k0 + colk, T - 8);
      gload_lds16(vth + (size_t)dr * T + tc, Vb + (size_t)(r * 256) * 8 + wbase8);
    }
  };

  stage(0, 0);
  __syncthreads();  // drain prologue loads (vmcnt(0) implied)

  int cur = 0;
  for (int kt = 0; kt < nkt; ++kt) {
    // issue next tile's loads; they drain at this iter's closing barrier
    if (kt + 1 < nkt) stage(cur ^ 1, kt + 1);

    const unsigned short* Kb = smem + cur * 8192;
    const unsigned short* Vb = smem + 16384 + cur * 8192;

    // ---- S^T = K * Q^T ----
    f32x16 st0, st1;
#pragma unroll
    for (int r = 0; r < 16; ++r) { st0[r] = 0.0f; st1[r] = 0.0f; }
    __builtin_amdgcn_s_setprio(1);
#pragma unroll
    for (int s = 0; s < 8; ++s) {
      {
        const int key = lo;
        const int idx = (key * DD + s * 16 + hi * 8) ^ ((key & 7) << 3);
        s16x8 kf = *(const s16x8*)(&Kb[idx]);
        st0 = __builtin_amdgcn_mfma_f32_32x32x16_bf16(kf, qf[s], st0, 0, 0, 0);
      }
      {
        const int key = 32 + lo;
        const int idx = (key * DD + s * 16 + hi * 8) ^ ((key & 7) << 3);
        s16x8 kf = *(const s16x8*)(&Kb[idx]);
        st1 = __builtin_amdgcn_mfma_f32_32x32x16_bf16(kf, qf[s], st1, 0, 0, 0);
      }
    }
    __builtin_amdgcn_s_setprio(0);

    // mask keys beyond nk (last partial tile only)
    if (kt * KVB + KVB > nk) {
#pragma unroll
      for (int r = 0; r < 16; ++r) {
        const int base = (r & 3) + 8 * (r >> 2) + 4 * hi;
        if (kt * KVB + base >= nk) st0[r] = -__builtin_inff();
        if (kt * KVB + 32 + base >= nk) st1[r] = -__builtin_inff();
      }
    }

    // ---- online softmax with defer-max (THR=8 in log2 domain) ----
    float tmax = -__builtin_inff();
#pragma unroll
    for (int r = 0; r < 16; ++r) tmax = fmaxf(tmax, fmaxf(st0[r], st1[r]));
    tmax = fmaxf(tmax, __shfl_xor(tmax, 32));

    if (!__all(tmax <= m_run + 8.0f)) {
      const float m_new = fmaxf(m_run, tmax);
      const float alpha = __builtin_amdgcn_exp2f(m_run - m_new);
      l_run *= alpha;
      m_run = m_new;
#pragma unroll
      for (int r = 0; r < 16; ++r) {
        const int src = (r & 3) + 8 * (r >> 2) + 4 * hi;
        const float af = __shfl(alpha, src);
        Oa[0][r] *= af; Oa[1][r] *= af; Oa[2][r] *= af; Oa[3][r] *= af;
      }
    }

    float p[32];
    float psum = 0.0f;
#pragma unroll
    for (int r = 0; r < 16; ++r) {
      p[r] = __builtin_amdgcn_exp2f(st0[r] - m_run);
      p[16 + r] = __builtin_amdgcn_exp2f(st1[r] - m_run);
      psum += p[r] + p[16 + r];
    }
    psum += __shfl_xor(psum, 32);
    l_run += psum;

    // ---- pack P to bf16 (cvt_pk) ----
    // chunk c (0..7): keys 8c+4hi+e, e=0..3 -> p[(c>>2)*16 + 4*(c&3) + e]
    uint32_t ownu[16];
#pragma unroll
    for (int c = 0; c < 8; ++c) {
      const int t = c >> 2, rb = 4 * (c & 3);
      uint32_t w0, w1;
      asm("v_cvt_pk_bf16_f32 %0, %1, %2" : "=v"(w0) : "v"(p[t * 16 + rb + 0]), "v"(p[t * 16 + rb + 1]));
      asm("v_cvt_pk_bf16_f32 %0, %1, %2" : "=v"(w1) : "v"(p[t * 16 + rb + 2]), "v"(p[t * 16 + rb + 3]));
      ownu[c * 2 + 0] = w0;
      ownu[c * 2 + 1] = w1;
    }

    // ---- O += P * V  (A-frag assembled via permlane32_swap) ----
    __builtin_amdgcn_s_setprio(1);
#pragma unroll
    for (int ks2 = 0; ks2 < 4; ++ks2) {
      uint32_t a0 = ownu[4 * ks2 + 0], b0 = ownu[4 * ks2 + 2];
      uint32_t a1 = ownu[4 * ks2 + 1], b1 = ownu[4 * ks2 + 3];
      asm("v_permlane32_swap_b32 %0, %1" : "+v"(a0), "+v"(b0));
      asm("v_permlane32_swap_b32 %0, %1" : "+v"(a1), "+v"(b1));
      union { uint32_t u[4]; s16x8 v; } pu;
      pu.u[0] = a0; pu.u[1] = a1; pu.u[2] = b0; pu.u[3] = b1;
#pragma unroll
      for (int dt = 0; dt < 4; ++dt) {
        const int d = dt * 32 + lo;
        const int idx = (d * KVB + ks2 * 16 + hi * 8) ^ ((d & 7) << 3);
        s16x8 vf = *(const s16x8*)(&Vb[idx]);
        Oa[dt] = __builtin_amdgcn_mfma_f32_32x32x16_bf16(pu.v, vf, Oa[dt], 0, 0, 0);
      }
    }
    __builtin_amdgcn_s_setprio(0);

    if (kt + 1 < nkt) {
      __syncthreads();  // drains this iter's stage loads (vmcnt(0)) + syncs waves
      cur ^= 1;
    }
  }

  // ---- epilogue: out[q] = O[q]/l ----
  const float linv = 1.0f / l_run;
#pragma unroll
  for (int r = 0; r < 16; ++r) {
    const int src = (r & 3) + 8 * (r >> 2) + 4 * hi;
    const float li = __shfl(linv, src);
    const int qirow = qt * QBLK + wave * 32 + src;
    if (qirow < nq) {
      float* op = out + ((size_t)(qs + qirow) * HH + h) * DD;
      op[0 * 32 + lo] = Oa[0][r] * li;
      op[1 * 32 + lo] = Oa[1][r] * li;
      op[2 * 32 + lo] = Oa[2][r] * li;
      op[3 * 32 + lo] = Oa[3][r] * li;
    }
  }
}

extern "C" void kernel_launch(void* const* d_in, const int* in_sizes, int n_in,
                              void* d_out, int out_size, void* d_ws, size_t ws_size,
                              hipStream_t stream) {
  const float* q = (const float*)d_in[0];
  const float* k = (const float*)d_in[1];
  const float* v = (const float*)d_in[2];
  const int* cuq = (const int*)d_in[3];
  const int* cuk = (const int*)d_in[4];
  float* out = (float*)d_out;
  const int T = in_sizes[0] / (HH * DD);
  const int B = in_sizes[3] - 1;

  hipMemsetAsync(d_out, 0, (size_t)out_size * sizeof(float), stream);

  unsigned short* kb = (unsigned short*)d_ws;
  unsigned short* vt = kb + (size_t)T * HH * DD;
  const size_t need = (size_t)T * HH * DD * 2 * 2;
  if (ws_size < need) return;

  {
    long total4 = (long)T * HH * DD / 4;
    int blocks = (int)((total4 + 255) / 256);
    kconv<<<blocks, 256, 0, stream>>>(k, kb, T);
  }
  {
    dim3 g((unsigned)((T + 63) / 64), DD / 64, HH);
    vtrans<<<g, 256, 0, stream>>>(v, vt, T);
  }
  {
    const int BH = B * HH;
    const int scap = MAXSEQ < T ? MAXSEQ : T;
    const int qtiles = (scap + QBLK - 1) / QBLK;
    attn_main<<<BH * qtiles, 256, 65536, stream>>>(q, kb, vt, cuq, cuk, out, T, BH);
  }
}